// Round 1
// baseline (257.439 us; speedup 1.0000x reference)
//
#include <hip/hip_runtime.h>

// NSA compression attention fwd, MI355X/gfx950.  R4.
// R3 was latency-bound at 2 WG/CU (LDS 69.6 KB).  R4:
//  (a) single 34.8 KB LDS buffer reused K -> V^T (K dead after GEMM1)
//      -> 4 WG/CU, 16 waves/CU (__launch_bounds__(256,4), VGPR cap 128);
//  (b) causal guards on STAGING (not just GEMM): K staged it<c_max,
//      V^T staged cols < kbi_max*32 (valid global data; P=0 beyond nv);
//  (c) V^T staging packs column pairs -> ds_write_b32, conflict-free
//      (lanes span n -> 2 lanes/bank), half the write instructions.
// Lifecycle: [q loads + K stage] -> bar -> GEMM1 -> bar ->
//            [V stage (loads overlap softmax VALU) + softmax] -> bar ->
//            GEMM2 -> store.

#define Zc 4
#define Hc 16
#define Gc 4
#define Sc 4096
#define NBc 128
#define Dc 128
#define VST 136

typedef __attribute__((ext_vector_type(8))) short short8;   // 8 bf16
typedef __attribute__((ext_vector_type(4))) float float4v;  // 4 fp32

__device__ inline unsigned pk2bf(float a, float b) {
    union { float f; unsigned u; } x, y; x.f = a; y.f = b;
    return __builtin_amdgcn_perm(y.u + 0x8000u, x.u + 0x8000u, 0x07060302u);
}
__device__ inline short8 mkfrag(float4v f0, float4v f1) {
    union { short8 v; unsigned d[4]; } u;
    u.d[0] = pk2bf(f0[0], f0[1]);
    u.d[1] = pk2bf(f0[2], f0[3]);
    u.d[2] = pk2bf(f1[0], f1[1]);
    u.d[3] = pk2bf(f1[2], f1[3]);
    return u.v;
}

__global__ __launch_bounds__(256, 4)
void nsa_fwd(const float* __restrict__ q, const float* __restrict__ kb,
             const float* __restrict__ vb, float* __restrict__ out) {
    // One buffer, two lives: K rows [n][d] for GEMM1, then V^T [d][n] for GEMM2.
    __shared__ __align__(16) short KV[NBc * VST];   // 34816 B -> 4 WG/CU

    const int bx   = blockIdx.x, m0 = bx * 128;
    const int h    = blockIdx.y, z = blockIdx.z, g = h >> 2;
    const int tid  = threadIdx.x;
    const int wq   = tid >> 6;
    const int lane = tid & 63;
    const int l16  = lane & 15;
    const int quad = lane >> 4;

    const int nvmax   = 4 * bx + 4;            // max valid blocks for this tile
    const int c_max   = (nvmax + 15) >> 4;     // 16-block j-tiles needed
    const int kbi_max = (nvmax + 31) >> 5;     // 32-block K-chunks for GEMM2
    const int nstage  = kbi_max << 5;          // V^T columns to stage

    // ---- hoisted q loads: the HBM stream, issued first ----
    const float* qbase = q + ((size_t)(z * Hc + h) * Sc + m0 + wq * 32) * Dc;
    float4v qraw[4][2][2];
    #pragma unroll
    for (int dk = 0; dk < 4; dk++)
        #pragma unroll
        for (int t = 0; t < 2; t++) {
            const float* s = qbase + (size_t)(t * 16 + l16) * Dc + dk * 32 + quad * 8;
            qraw[dk][t][0] = *(const float4v*)s;
            qraw[dk][t][1] = *(const float4v*)(s + 4);
        }

    // ---- stage K -> LDS bf16, coalesced, causally guarded ----
    const float* ksrc = kb + (size_t)(z * Gc + g) * NBc * Dc;
    #pragma unroll
    for (int it = 0; it < 8; it++)
        if (it < c_max) {                      // wave-uniform guard
            int i = it * 256 + tid;
            int n = i >> 4, c8 = i & 15;       // row, 8-float chunk
            const float* s = ksrc + (size_t)n * Dc + c8 * 8;
            float4v f0 = *(const float4v*)s, f1 = *(const float4v*)(s + 4);
            *(short8*)(KV + n * VST + c8 * 8) = mkfrag(f0, f1);
        }

    // ---- convert q -> bf16 frags, sm_scale folded in ----
    const float sm = 0.08838834764831845f;     // 1/sqrt(128)
    short8 qf[4][2];
    #pragma unroll
    for (int dk = 0; dk < 4; dk++)
        #pragma unroll
        for (int t = 0; t < 2; t++)
            qf[dk][t] = mkfrag(qraw[dk][t][0] * sm, qraw[dk][t][1] * sm);

    __syncthreads();   // barrier 1: K visible

    // ---- GEMM1: S^T = K * Q^T  (A=K rows from LDS, B=q frags in regs) ----
    float4v acc[8][2];   // C: col=l16=query, row=quad*4+r = block j (within c*16)
    #pragma unroll
    for (int c = 0; c < 8; c++)
        #pragma unroll
        for (int t = 0; t < 2; t++) acc[c][t] = (float4v)0.f;

    #pragma unroll
    for (int dk = 0; dk < 4; dk++)
        #pragma unroll
        for (int c = 0; c < 8; c++)
            if (c < c_max) {
                short8 a = *(const short8*)(KV + (c * 16 + l16) * VST + dk * 32 + quad * 8);
                acc[c][0] = __builtin_amdgcn_mfma_f32_16x16x32_bf16(a, qf[dk][0], acc[c][0], 0, 0, 0);
                acc[c][1] = __builtin_amdgcn_mfma_f32_16x16x32_bf16(a, qf[dk][1], acc[c][1], 0, 0, 0);
            }

    __syncthreads();   // barrier 2: all waves done reading K from LDS

    // ---- stage V^T -> LDS bf16 (overwrites K), column-pair packed, guarded ----
    // Lanes span column pairs (np=lane) -> banks np%32, 2 lanes/bank = free.
    // Row c*4+k2 is wave-uniform (c = it*4 + wq).
    {
        const float* vsrc = vb + (size_t)(z * Gc + g) * NBc * Dc;
        const int np = tid & 63, n2 = np * 2;
        const bool vact = (n2 < nstage);       // per-lane causal guard
        #pragma unroll
        for (int it = 0; it < 8; it++) {
            const int c = it * 4 + wq;         // d-chunk of 4, wave-uniform
            if (vact) {
                float4v fa = *(const float4v*)(vsrc + (size_t)n2 * Dc + c * 4);
                float4v fb = *(const float4v*)(vsrc + (size_t)(n2 + 1) * Dc + c * 4);
                #pragma unroll
                for (int k2 = 0; k2 < 4; k2++)
                    *(unsigned*)(KV + (c * 4 + k2) * VST + n2) = pk2bf(fa[k2], fb[k2]);
            }
        }
    }

    // ---- softmax over blocks + normalize + pack bf16 (overlaps V latency) ----
    unsigned Ppk[8][2][2];
    #pragma unroll
    for (int c = 0; c < 8; c++)
        #pragma unroll
        for (int t = 0; t < 2; t++) { Ppk[c][t][0] = 0u; Ppk[c][t][1] = 0u; }

    #pragma unroll
    for (int t = 0; t < 2; t++) {
        const int mg = m0 + wq * 32 + t * 16 + l16;
        int nv = (mg + 1) >> 5; if (nv > NBc) nv = NBc;
        float mx = -1e30f;
        #pragma unroll
        for (int c = 0; c < 8; c++)
            if (c < c_max)
                #pragma unroll
                for (int r = 0; r < 4; r++) {
                    const int j = c * 16 + quad * 4 + r;
                    float s = acc[c][t][r];
                    s = (j < nv) ? s : -1e30f;
                    acc[c][t][r] = s;
                    mx = fmaxf(mx, s);
                }
        mx = fmaxf(mx, __shfl_xor(mx, 16, 64));
        mx = fmaxf(mx, __shfl_xor(mx, 32, 64));
        float ls = 0.f;
        #pragma unroll
        for (int c = 0; c < 8; c++)
            if (c < c_max)
                #pragma unroll
                for (int r = 0; r < 4; r++) {
                    float s = acc[c][t][r];
                    float p = (s > -1e29f) ? __expf(s - mx) : 0.f;
                    acc[c][t][r] = p;
                    ls += p;
                }
        ls += __shfl_xor(ls, 16, 64);
        ls += __shfl_xor(ls, 32, 64);
        const float inv = (ls > 0.f) ? 1.f / ls : 0.f;
        #pragma unroll
        for (int c = 0; c < 8; c++)
            if (c < c_max) {
                Ppk[c][t][0] = pk2bf(acc[c][t][0] * inv, acc[c][t][1] * inv);
                Ppk[c][t][1] = pk2bf(acc[c][t][2] * inv, acc[c][t][3] * inv);
            }
    }

    __syncthreads();   // barrier 3: V^T visible

    // ---- GEMM2: O = P * V.  A = P via quad-shuffle C->A transform; B = V^T LDS ----
    float4v oacc[8][2];
    #pragma unroll
    for (int c = 0; c < 8; c++)
        #pragma unroll
        for (int t = 0; t < 2; t++) oacc[c][t] = (float4v)0.f;

    const int s0 = (((2 * quad) & 3) << 4) | l16;
    const int s1 = (((2 * quad + 1) & 3) << 4) | l16;
    const bool hi = (quad >= 2);

    #pragma unroll
    for (int kbi = 0; kbi < 4; kbi++)
        if (kbi < kbi_max) {
            short8 ap[2];
            #pragma unroll
            for (int t = 0; t < 2; t++) {
                const int c1 = 2 * kbi;
                unsigned w0a = (unsigned)__shfl((int)Ppk[c1    ][t][0], s0, 64);
                unsigned w0b = (unsigned)__shfl((int)Ppk[c1 + 1][t][0], s0, 64);
                unsigned w1a = (unsigned)__shfl((int)Ppk[c1    ][t][1], s0, 64);
                unsigned w1b = (unsigned)__shfl((int)Ppk[c1 + 1][t][1], s0, 64);
                unsigned w2a = (unsigned)__shfl((int)Ppk[c1    ][t][0], s1, 64);
                unsigned w2b = (unsigned)__shfl((int)Ppk[c1 + 1][t][0], s1, 64);
                unsigned w3a = (unsigned)__shfl((int)Ppk[c1    ][t][1], s1, 64);
                unsigned w3b = (unsigned)__shfl((int)Ppk[c1 + 1][t][1], s1, 64);
                union { short8 v; unsigned d[4]; } u;
                u.d[0] = hi ? w0b : w0a;
                u.d[1] = hi ? w1b : w1a;
                u.d[2] = hi ? w2b : w2a;
                u.d[3] = hi ? w3b : w3a;
                ap[t] = u.v;
            }
            #pragma unroll
            for (int c = 0; c < 8; c++) {
                short8 bv = *(const short8*)(KV + (c * 16 + l16) * VST + kbi * 32 + quad * 8);
                #pragma unroll
                for (int t = 0; t < 2; t++)
                    oacc[c][t] = __builtin_amdgcn_mfma_f32_16x16x32_bf16(ap[t], bv, oacc[c][t], 0, 0, 0);
            }
        }

    // ---- store (P pre-normalized): C row=quad*4+rr = query, col=l16 = dv ----
    float* obase = out + ((size_t)(z * Hc + h) * Sc + m0 + wq * 32) * Dc;
    #pragma unroll
    for (int t = 0; t < 2; t++)
        #pragma unroll
        for (int rr = 0; rr < 4; rr++) {
            const int row = t * 16 + quad * 4 + rr;
            #pragma unroll
            for (int c = 0; c < 8; c++)
                obase[(size_t)row * Dc + c * 16 + l16] = oacc[c][t][rr];
        }
}

extern "C" void kernel_launch(void* const* d_in, const int* in_sizes, int n_in,
                              void* d_out, int out_size, void* d_ws, size_t ws_size,
                              hipStream_t stream) {
    const float* q  = (const float*)d_in[0];
    const float* kb = (const float*)d_in[1];
    const float* vb = (const float*)d_in[2];
    // d_in[3] = block_ends; analytic: block j valid iff j < (m+1)>>5
    float* out = (float*)d_out;
    dim3 grid(Sc / 128, Hc, Zc);
    nsa_fwd<<<grid, dim3(256), 0, stream>>>(q, kb, vb, out);
}